// Round 2
// baseline (490.256 us; speedup 1.0000x reference)
//
#include <hip/hip_runtime.h>

typedef __attribute__((ext_vector_type(8))) short short8;
typedef __attribute__((ext_vector_type(4))) float f32x4;

#define LOG2E 1.44269504088896340736f

__device__ __forceinline__ unsigned short f2bf(float f) {
    union { float f; unsigned u; } a; a.f = f;
    unsigned r = a.u + 0x7fffu + ((a.u >> 16) & 1u);   // RNE
    return (unsigned short)(r >> 16);
}
__device__ __forceinline__ unsigned pk2(float x, float y) {
    return (unsigned)f2bf(x) | ((unsigned)f2bf(y) << 16);
}
__device__ __forceinline__ float fsigmoid(float x) {
    return __builtin_amdgcn_rcpf(1.0f + __builtin_amdgcn_exp2f(-LOG2E * x));
}

// B=2048, T=512, I=64, H=32. One wave per batch row; 4 waves per block.
// Lane j owns gate rows j (i|f) and j+64 (g|o).
__global__ __launch_bounds__(256, 2) void lstm_fused(
    const float* __restrict__ x,    // [2048,512,64]
    const float* __restrict__ Wih,  // [128,64]
    const float* __restrict__ Whh,  // [128,32]
    const float* __restrict__ bih,  // [128]
    const float* __restrict__ bhh,  // [128]
    const float* __restrict__ Wfc,  // [1,32]
    const float* __restrict__ bfc,  // [1]
    float* __restrict__ out)        // [2048,1]
{
    // W_ih bf16, row stride 80 shorts (160 B) to break bank conflicts on B-frag reads
    __shared__ unsigned short Wlds[128 * 80];          // 20480 B
    __shared__ float xg_sh[4 * 16 * 132];              // per-wave 16 t x (128 gates + pad), 33792 B
    __shared__ float h_sh[4 * 32];                     // per-wave h broadcast, 512 B

    const int tid  = threadIdx.x;
    const int lane = tid & 63;
    const int wv   = tid >> 6;
    const int b    = blockIdx.x * 4 + wv;

    // ---- cooperative W_ih -> LDS (bf16, padded rows) ----
    {
        const float4* w4 = (const float4*)Wih;
        unsigned* wl = (unsigned*)Wlds;
        #pragma unroll
        for (int i = 0; i < 8; i++) {
            int fi = tid * 8 + i;            // float4 index, 2048 total
            int g  = fi >> 4;                // gate row
            int k  = (fi & 15) << 2;         // col (float units)
            float4 v = w4[fi];
            wl[g * 40 + (k >> 1) + 0] = pk2(v.x, v.y);
            wl[g * 40 + (k >> 1) + 1] = pk2(v.z, v.w);
        }
    }

    // ---- per-lane recurrent weights (rows j and j+64) ----
    float w0[32], w1[32];
    {
        const float4* wh4 = (const float4*)Whh;
        #pragma unroll
        for (int i = 0; i < 8; i++) {
            float4 v = wh4[lane * 8 + i];
            w0[4*i+0] = v.x; w0[4*i+1] = v.y; w0[4*i+2] = v.z; w0[4*i+3] = v.w;
        }
        #pragma unroll
        for (int i = 0; i < 8; i++) {
            float4 v = wh4[(lane + 64) * 8 + i];
            w1[4*i+0] = v.x; w1[4*i+1] = v.y; w1[4*i+2] = v.z; w1[4*i+3] = v.w;
        }
    }
    const float bias0 = bih[lane]      + bhh[lane];
    const float bias1 = bih[lane + 64] + bhh[lane + 64];
    const float kmul  = (lane < 32) ? 2.0f : 1.0f;   // tanh on g-rows (lanes<32 second gate)
    const float ksub  = (lane < 32) ? 1.0f : 0.0f;

    __syncthreads();  // Wlds ready; no further barriers (per-wave LDS regions are private)

    const int m    = lane & 15;   // A-row (timestep) / B-col (gate) index
    const int quad = lane >> 4;   // k-quad

    const float* xrow = x + ((size_t)b * 512 + m) * 64;
    float* xgw = xg_sh + wv * 2112;
    float* hw  = h_sh  + wv * 32;

    float hr[32];
    #pragma unroll
    for (int k = 0; k < 32; k++) hr[k] = 0.0f;
    float c = 0.0f, h = 0.0f;

    for (int ch = 0; ch < 32; ++ch) {
        // ---- stage x chunk as two A-frags (k 0..31, 32..63), bf16 ----
        const float4* xr4 = (const float4*)(xrow + ch * 1024);
        float4 l0 = xr4[quad * 2];
        float4 l1 = xr4[quad * 2 + 1];
        float4 l2 = xr4[8 + quad * 2];
        float4 l3 = xr4[8 + quad * 2 + 1];
        union { short8 v; unsigned u[4]; } A0, A1;
        A0.u[0] = pk2(l0.x, l0.y); A0.u[1] = pk2(l0.z, l0.w);
        A0.u[2] = pk2(l1.x, l1.y); A0.u[3] = pk2(l1.z, l1.w);
        A1.u[0] = pk2(l2.x, l2.y); A1.u[1] = pk2(l2.z, l2.w);
        A1.u[2] = pk2(l3.x, l3.y); A1.u[3] = pk2(l3.z, l3.w);

        // ---- xg[16 t][128 g] via 16 MFMAs; scatter pairs (g, g+64) adjacent ----
        #pragma unroll
        for (int n = 0; n < 8; n++) {
            const short8 B0 = *(const short8*)&Wlds[(16 * n + m) * 80 + quad * 8];
            const short8 B1 = *(const short8*)&Wlds[(16 * n + m) * 80 + 32 + quad * 8];
            f32x4 acc = {0.f, 0.f, 0.f, 0.f};
            acc = __builtin_amdgcn_mfma_f32_16x16x32_bf16(A0.v, B0, acc, 0, 0, 0);
            acc = __builtin_amdgcn_mfma_f32_16x16x32_bf16(A1.v, B1, acc, 0, 0, 0);
            // gate = 16n + m; pos: gate<64 -> 2*gate, gate>=64 -> 2*(gate-64)+1
            const int pos = ((n & 3) << 5) + 2 * m + (n >> 2);
            #pragma unroll
            for (int r = 0; r < 4; r++)
                xgw[(quad * 4 + r) * 132 + pos] = acc[r];
        }

        // ---- 16 recurrent timesteps ----
        #pragma unroll 2
        for (int tt = 0; tt < 16; ++tt) {
            const float2 xg2 = *(const float2*)&xgw[tt * 132 + 2 * lane];
            float g0 = bias0 + xg2.x;
            float g1 = bias1 + xg2.y;
            #pragma unroll
            for (int k = 0; k < 32; k++) {
                g0 = fmaf(w0[k], hr[k], g0);
                g1 = fmaf(w1[k], hr[k], g1);
            }
            const float s0 = fsigmoid(g0);                  // i (lo) | f (hi)
            const float v1 = fsigmoid(g1 * kmul);
            const float s1 = fmaf(v1, kmul, -ksub);         // tanh g (lo) | o (hi)
            const float f_ = __shfl(s0, lane ^ 32);         // f for lanes<32
            const float o_ = __shfl(s1, lane ^ 32);         // o for lanes<32
            c = fmaf(f_, c, s0 * s1);                       // valid in lanes<32
            const float th = fmaf(2.0f, fsigmoid(2.0f * c), -1.0f);
            h = o_ * th;
            if (lane < 32) hw[lane] = h;
            #pragma unroll
            for (int i = 0; i < 8; i++) {
                float4 hv = *(const float4*)&hw[i * 4];
                hr[4*i+0] = hv.x; hr[4*i+1] = hv.y; hr[4*i+2] = hv.z; hr[4*i+3] = hv.w;
            }
        }
    }

    // ---- fused fc: out[b] = sum_j h_j * Wfc[j] + bfc ----
    float p = (lane < 32) ? h * Wfc[lane & 31] : 0.0f;
    #pragma unroll
    for (int msk = 16; msk >= 1; msk >>= 1) p += __shfl_xor(p, msk);
    if (lane == 0) out[b] = p + bfc[0];
}

extern "C" void kernel_launch(void* const* d_in, const int* in_sizes, int n_in,
                              void* d_out, int out_size, void* d_ws, size_t ws_size,
                              hipStream_t stream) {
    const float* x   = (const float*)d_in[0];
    const float* Wih = (const float*)d_in[1];
    const float* Whh = (const float*)d_in[2];
    const float* bih = (const float*)d_in[3];
    const float* bhh = (const float*)d_in[4];
    const float* Wfc = (const float*)d_in[5];
    const float* bfc = (const float*)d_in[6];
    float* out = (float*)d_out;
    lstm_fused<<<dim3(512), dim3(256), 0, stream>>>(x, Wih, Whh, bih, bhh, Wfc, bfc, out);
}

// Round 3
// 477.208 us; speedup vs baseline: 1.0273x; 1.0273x over previous
//
#include <hip/hip_runtime.h>

typedef __attribute__((ext_vector_type(8))) short short8;
typedef __attribute__((ext_vector_type(4))) float f32x4;

#define LOG2E 1.44269504088896340736f

__device__ __forceinline__ unsigned short f2bf(float f) {
    union { float f; unsigned u; } a; a.f = f;
    unsigned r = a.u + 0x7fffu + ((a.u >> 16) & 1u);   // RNE
    return (unsigned short)(r >> 16);
}
__device__ __forceinline__ unsigned pk2(float x, float y) {
    return (unsigned)f2bf(x) | ((unsigned)f2bf(y) << 16);
}

// B=2048, T=512, I=64, H=32. One wave per batch row; 4 waves per block.
// Lane j owns gates j (i|f) and j+64 (g|o). Recurrent matvec h·W_hh^T via
// row-broadcast MFMA: all A-rows = h, 8 n-tiles cover 128 gates, K=32=H.
__global__ __launch_bounds__(256, 2) void lstm_fused(
    const float* __restrict__ x,    // [2048,512,64]
    const float* __restrict__ Wih,  // [128,64]
    const float* __restrict__ Whh,  // [128,32]
    const float* __restrict__ bih,  // [128]
    const float* __restrict__ bhh,  // [128]
    const float* __restrict__ Wfc,  // [1,32]
    const float* __restrict__ bfc,  // [1]
    float* __restrict__ out)        // [2048,1]
{
    __shared__ unsigned short Wlds[128 * 80];            // W_ih bf16, row stride 80 (bank-safe)
    __shared__ float xg_sh[4 * 16 * 132];                // per-wave xg chunk (bias folded in)
    __shared__ alignas(64) unsigned short hbuf[4 * 32];  // per-wave h bf16 broadcast

    const int tid  = threadIdx.x;
    const int lane = tid & 63;
    const int wv   = tid >> 6;
    const int b    = blockIdx.x * 4 + wv;
    const int m    = lane & 15;   // col within n-tile / A-row / timestep idx
    const int quad = lane >> 4;   // k-quad

    // ---- cooperative W_ih -> LDS (bf16, padded rows) ----
    {
        const float4* w4 = (const float4*)Wih;
        unsigned* wl = (unsigned*)Wlds;
        #pragma unroll
        for (int i = 0; i < 8; i++) {
            int fi = tid * 8 + i;            // float4 index, 2048 total
            int g  = fi >> 4;                // gate row
            int k  = (fi & 15) << 2;         // col (float units)
            float4 v = w4[fi];
            wl[g * 40 + (k >> 1) + 0] = pk2(v.x, v.y);
            wl[g * 40 + (k >> 1) + 1] = pk2(v.z, v.w);
        }
    }

    // ---- W_hh B-frags in registers (bf16): tile t, lane holds Whh[16t+m][quad*8..+7] ----
    short8 Bh[8];
    #pragma unroll
    for (int t = 0; t < 8; t++) {
        const float4* wr = (const float4*)(Whh + (size_t)(16 * t + m) * 32 + quad * 8);
        float4 va = wr[0], vb = wr[1];
        union { short8 v; unsigned u[4]; } B;
        B.u[0] = pk2(va.x, va.y); B.u[1] = pk2(va.z, va.w);
        B.u[2] = pk2(vb.x, vb.y); B.u[3] = pk2(vb.z, vb.w);
        Bh[t] = B.v;
    }

    // ---- per-lane scatter bias: biasv[n] = bih[16n+m]+bhh[16n+m] ----
    float biasv[8];
    #pragma unroll
    for (int n = 0; n < 8; n++) biasv[n] = bih[16 * n + m] + bhh[16 * n + m];

    const float kmul = (lane < 32) ? 2.0f : 1.0f;   // tanh trick on g-gate half
    const float ksub = (lane < 32) ? 1.0f : 0.0f;
    const float kl   = -LOG2E * kmul;
    const bool  q0   = (lane & 16) != 0;
    const bool  q1   = (lane & 32) != 0;
    const bool  lo   = (lane < 32);

    __syncthreads();  // Wlds ready; per-wave regions need no further barriers

    const float* xrow = x + ((size_t)b * 512 + m) * 64;
    float* xgw = xg_sh + wv * 2112;
    unsigned short* hw = hbuf + wv * 32;

    hw[lane & 31] = 0;          // h=0 (2 lanes write same value: benign)
    float c = 0.0f, h = 0.0f;
    const f32x4 z4 = {0.f, 0.f, 0.f, 0.f};

    for (int ch = 0; ch < 32; ++ch) {
        // ---- stage x chunk as two A-frags (k 0..31, 32..63), bf16 ----
        const float4* xr4 = (const float4*)(xrow + ch * 1024);
        float4 l0 = xr4[quad * 2];
        float4 l1 = xr4[quad * 2 + 1];
        float4 l2 = xr4[8 + quad * 2];
        float4 l3 = xr4[8 + quad * 2 + 1];
        union { short8 v; unsigned u[4]; } A0, A1;
        A0.u[0] = pk2(l0.x, l0.y); A0.u[1] = pk2(l0.z, l0.w);
        A0.u[2] = pk2(l1.x, l1.y); A0.u[3] = pk2(l1.z, l1.w);
        A1.u[0] = pk2(l2.x, l2.y); A1.u[1] = pk2(l2.z, l2.w);
        A1.u[2] = pk2(l3.x, l3.y); A1.u[3] = pk2(l3.z, l3.w);

        // ---- xg[16 t][128 g] via 16 MFMAs; scatter (g, g+64) adjacent, bias folded ----
        #pragma unroll
        for (int n = 0; n < 8; n++) {
            const short8 B0 = *(const short8*)&Wlds[(16 * n + m) * 80 + quad * 8];
            const short8 B1 = *(const short8*)&Wlds[(16 * n + m) * 80 + 32 + quad * 8];
            f32x4 acc = {0.f, 0.f, 0.f, 0.f};
            acc = __builtin_amdgcn_mfma_f32_16x16x32_bf16(A0.v, B0, acc, 0, 0, 0);
            acc = __builtin_amdgcn_mfma_f32_16x16x32_bf16(A1.v, B1, acc, 0, 0, 0);
            const int pos = ((n & 3) << 5) + 2 * m + (n >> 2);
            #pragma unroll
            for (int r = 0; r < 4; r++)
                xgw[(quad * 4 + r) * 132 + pos] = acc[r] + biasv[n];
        }

        // ---- 16 recurrent timesteps ----
        #pragma unroll
        for (int tt = 0; tt < 16; ++tt) {
            // h (bf16) broadcast: A-rows all equal h -> quad reads k-chunk quad*8..+7
            const short8 abf = *(const short8*)&hw[quad * 8];
            const f32x4 a0 = __builtin_amdgcn_mfma_f32_16x16x32_bf16(abf, Bh[0], z4, 0, 0, 0);
            const f32x4 a1 = __builtin_amdgcn_mfma_f32_16x16x32_bf16(abf, Bh[1], z4, 0, 0, 0);
            const f32x4 a2 = __builtin_amdgcn_mfma_f32_16x16x32_bf16(abf, Bh[2], z4, 0, 0, 0);
            const f32x4 a3 = __builtin_amdgcn_mfma_f32_16x16x32_bf16(abf, Bh[3], z4, 0, 0, 0);
            const f32x4 a4 = __builtin_amdgcn_mfma_f32_16x16x32_bf16(abf, Bh[4], z4, 0, 0, 0);
            const f32x4 a5 = __builtin_amdgcn_mfma_f32_16x16x32_bf16(abf, Bh[5], z4, 0, 0, 0);
            const f32x4 a6 = __builtin_amdgcn_mfma_f32_16x16x32_bf16(abf, Bh[6], z4, 0, 0, 0);
            const f32x4 a7 = __builtin_amdgcn_mfma_f32_16x16x32_bf16(abf, Bh[7], z4, 0, 0, 0);
            // lane j's gate j is in tile j>>4 (col auto-matches); gate j+64 in tile 4+(j>>4)
            const float hh0 = q1 ? (q0 ? a3[0] : a2[0]) : (q0 ? a1[0] : a0[0]);
            const float hh1 = q1 ? (q0 ? a7[0] : a6[0]) : (q0 ? a5[0] : a4[0]);

            const float2 xg2 = *(const float2*)&xgw[tt * 132 + 2 * lane];
            const float g0 = xg2.x + hh0;
            const float g1 = xg2.y + hh1;

            const float s0 = __builtin_amdgcn_rcpf(1.0f + __builtin_amdgcn_exp2f(-LOG2E * g0));
            const float v1 = __builtin_amdgcn_rcpf(1.0f + __builtin_amdgcn_exp2f(kl * g1));
            const float s1 = fmaf(v1, kmul, -ksub);          // tanh g (lo) | o (hi)
            const float f_ = __shfl(s0, lane ^ 32);
            const float o_ = __shfl(s1, lane ^ 32);
            // all lanes compute c,h for column (lane&31) (operand-commuted, identical)
            const float ui = lo ? s0 : f_;   // i
            const float vg = lo ? s1 : o_;   // tanh g
            const float wf = lo ? f_ : s0;   // f
            c = fmaf(wf, c, ui * vg);
            const float th = fmaf(2.0f, __builtin_amdgcn_rcpf(
                                 1.0f + __builtin_amdgcn_exp2f(-2.0f * LOG2E * c)), -1.0f);
            const float oo = lo ? o_ : s1;   // o
            h = oo * th;
            hw[lane & 31] = f2bf(h);         // 2 lanes write same value: benign
        }
    }

    // ---- fused fc: out[b] = sum_j h_j * Wfc[j] + bfc ----
    float p = lo ? h * Wfc[lane & 31] : 0.0f;
    #pragma unroll
    for (int msk = 16; msk >= 1; msk >>= 1) p += __shfl_xor(p, msk);
    if (lane == 0) out[b] = p + bfc[0];
}

extern "C" void kernel_launch(void* const* d_in, const int* in_sizes, int n_in,
                              void* d_out, int out_size, void* d_ws, size_t ws_size,
                              hipStream_t stream) {
    const float* x   = (const float*)d_in[0];
    const float* Wih = (const float*)d_in[1];
    const float* Whh = (const float*)d_in[2];
    const float* bih = (const float*)d_in[3];
    const float* bhh = (const float*)d_in[4];
    const float* Wfc = (const float*)d_in[5];
    const float* bfc = (const float*)d_in[6];
    float* out = (float*)d_out;
    lstm_fused<<<dim3(512), dim3(256), 0, stream>>>(x, Wih, Whh, bih, bhh, Wfc, bfc, out);
}

// Round 4
// 431.633 us; speedup vs baseline: 1.1358x; 1.1056x over previous
//
#include <hip/hip_runtime.h>

typedef __attribute__((ext_vector_type(8))) short short8;
typedef __attribute__((ext_vector_type(4))) float f32x4;

#define LOG2E 1.44269504088896340736f

__device__ __forceinline__ unsigned short f2bf(float f) {
    union { float f; unsigned u; } a; a.f = f;
    unsigned r = a.u + 0x7fffu + ((a.u >> 16) & 1u);   // RNE
    return (unsigned short)(r >> 16);
}
__device__ __forceinline__ unsigned pk2(float x, float y) {
    return (unsigned)f2bf(x) | ((unsigned)f2bf(y) << 16);
}
__device__ __forceinline__ float sigm(float x) {       // sigmoid via exp2+rcp
    return __builtin_amdgcn_rcpf(1.0f + __builtin_amdgcn_exp2f(-LOG2E * x));
}

// B=2048, T=512, I=64, H=32. One wave per batch row; 4 waves per block.
// Lane j owns h-column cc=j&31 (duplicated across half-waves). Recurrent
// matvec h·W_hh^T via row-broadcast MFMA; with broadcast-A every lane holds
// gate 16t+(lane&15) for every tile t, so all 4 gates of column cc are
// selectable in-lane (no shfl in the recurrence chain).
__global__ __launch_bounds__(256, 2) void lstm_fused(
    const float* __restrict__ x,    // [2048,512,64]
    const float* __restrict__ Wih,  // [128,64]
    const float* __restrict__ Whh,  // [128,32]
    const float* __restrict__ bih,  // [128]
    const float* __restrict__ bhh,  // [128]
    const float* __restrict__ Wfc,  // [1,32]
    const float* __restrict__ bfc,  // [1]
    float* __restrict__ out)        // [2048,1]
{
    __shared__ unsigned short Wlds[128 * 80];            // W_ih bf16, stride 80 (bank-safe)
    __shared__ float xg_sh[4 * 16 * 132];                // per-wave xg: [16 t][4*cc+gidx], stride 132
    __shared__ alignas(64) unsigned short hbuf[4 * 32];  // per-wave h bf16 broadcast

    const int tid  = threadIdx.x;
    const int lane = tid & 63;
    const int wv   = tid >> 6;
    const int b    = blockIdx.x * 4 + wv;
    const int m    = lane & 15;   // tile col / timestep row
    const int quad = lane >> 4;   // k-quad
    const int cc   = lane & 31;   // owned h column

    // ---- cooperative W_ih -> LDS (bf16, padded rows) ----
    {
        const float4* w4 = (const float4*)Wih;
        unsigned* wl = (unsigned*)Wlds;
        #pragma unroll
        for (int i = 0; i < 8; i++) {
            int fi = tid * 8 + i;            // float4 index, 2048 total
            int g  = fi >> 4;                // gate row
            int k  = (fi & 15) << 2;         // col (float units)
            float4 v = w4[fi];
            wl[g * 40 + (k >> 1) + 0] = pk2(v.x, v.y);
            wl[g * 40 + (k >> 1) + 1] = pk2(v.z, v.w);
        }
    }

    // ---- W_hh B-frags in registers (bf16): tile t, lane holds Whh[16t+m][quad*8..+7] ----
    short8 Bh[8];
    #pragma unroll
    for (int t = 0; t < 8; t++) {
        const float4* wr = (const float4*)(Whh + (size_t)(16 * t + m) * 32 + quad * 8);
        float4 va = wr[0], vb = wr[1];
        union { short8 v; unsigned u[4]; } B;
        B.u[0] = pk2(va.x, va.y); B.u[1] = pk2(va.z, va.w);
        B.u[2] = pk2(vb.x, vb.y); B.u[3] = pk2(vb.z, vb.w);
        Bh[t] = B.v;
    }

    // ---- per-lane scatter bias: biasv[n] = bih[16n+m]+bhh[16n+m] ----
    float biasv[8];
    #pragma unroll
    for (int n = 0; n < 8; n++) biasv[n] = bih[16 * n + m] + bhh[16 * n + m];

    const bool b4 = (lane & 16) != 0;

    __syncthreads();  // Wlds ready; per-wave regions need no further barriers

    const float* xrow = x + ((size_t)b * 512 + m) * 64;
    float* xgw = xg_sh + wv * 2112;
    unsigned short* hw = hbuf + wv * 32;

    hw[cc] = 0;                 // h=0 (2 lanes write same value: benign)
    float c = 0.0f, h = 0.0f;
    const f32x4 z4 = {0.f, 0.f, 0.f, 0.f};

    // prefetch chunk 0
    float4 p0, p1, p2, p3;
    {
        const float4* xr4 = (const float4*)xrow;
        p0 = xr4[quad * 2];     p1 = xr4[quad * 2 + 1];
        p2 = xr4[8 + quad * 2]; p3 = xr4[8 + quad * 2 + 1];
    }

    for (int ch = 0; ch < 32; ++ch) {
        // ---- pack current chunk's A-frags (k 0..31, 32..63), bf16 ----
        union { short8 v; unsigned u[4]; } A0, A1;
        A0.u[0] = pk2(p0.x, p0.y); A0.u[1] = pk2(p0.z, p0.w);
        A0.u[2] = pk2(p1.x, p1.y); A0.u[3] = pk2(p1.z, p1.w);
        A1.u[0] = pk2(p2.x, p2.y); A1.u[1] = pk2(p2.z, p2.w);
        A1.u[2] = pk2(p3.x, p3.y); A1.u[3] = pk2(p3.z, p3.w);

        // ---- prefetch next chunk (covered by the 16-step loop below) ----
        {
            const int chn = (ch < 31) ? ch + 1 : 31;
            const float4* nx = (const float4*)(xrow + (size_t)chn * 1024);
            p0 = nx[quad * 2];     p1 = nx[quad * 2 + 1];
            p2 = nx[8 + quad * 2]; p3 = nx[8 + quad * 2 + 1];
        }

        // ---- xg[16 t] via 16 MFMAs; scatter to [tt][4*cc+gidx], bias folded ----
        // gate gg=16n+m -> gidx=n>>1, cc=16*(n&1)+m -> pos = 64*(n&1) + 4*m + (n>>1)
        #pragma unroll
        for (int n = 0; n < 8; n++) {
            const short8 B0 = *(const short8*)&Wlds[(16 * n + m) * 80 + quad * 8];
            const short8 B1 = *(const short8*)&Wlds[(16 * n + m) * 80 + 32 + quad * 8];
            f32x4 acc = {0.f, 0.f, 0.f, 0.f};
            acc = __builtin_amdgcn_mfma_f32_16x16x32_bf16(A0.v, B0, acc, 0, 0, 0);
            acc = __builtin_amdgcn_mfma_f32_16x16x32_bf16(A1.v, B1, acc, 0, 0, 0);
            const int pos = ((n & 1) << 6) + 4 * m + (n >> 1);
            #pragma unroll
            for (int r = 0; r < 4; r++)
                xgw[(quad * 4 + r) * 132 + pos] = acc[r] + biasv[n];
        }

        // ---- 16 recurrent timesteps ----
        #pragma unroll
        for (int tt = 0; tt < 16; ++tt) {
            // h (bf16) broadcast: all A-rows = h; quad reads k-chunk quad*8..+7
            const short8 abf = *(const short8*)&hw[quad * 8];
            const f32x4 a0 = __builtin_amdgcn_mfma_f32_16x16x32_bf16(abf, Bh[0], z4, 0, 0, 0);
            const f32x4 a1 = __builtin_amdgcn_mfma_f32_16x16x32_bf16(abf, Bh[1], z4, 0, 0, 0);
            const f32x4 a2 = __builtin_amdgcn_mfma_f32_16x16x32_bf16(abf, Bh[2], z4, 0, 0, 0);
            const f32x4 a3 = __builtin_amdgcn_mfma_f32_16x16x32_bf16(abf, Bh[3], z4, 0, 0, 0);
            const f32x4 a4 = __builtin_amdgcn_mfma_f32_16x16x32_bf16(abf, Bh[4], z4, 0, 0, 0);
            const f32x4 a5 = __builtin_amdgcn_mfma_f32_16x16x32_bf16(abf, Bh[5], z4, 0, 0, 0);
            const f32x4 a6 = __builtin_amdgcn_mfma_f32_16x16x32_bf16(abf, Bh[6], z4, 0, 0, 0);
            const f32x4 a7 = __builtin_amdgcn_mfma_f32_16x16x32_bf16(abf, Bh[7], z4, 0, 0, 0);
            // all C-rows equal -> lane holds gate 16t+(lane&15) for every tile t;
            // column cc's gates: i=cc (tile b4), f=cc+32 (2+b4), g=cc+64 (4+b4), o=cc+96 (6+b4)
            const float hi = b4 ? a1[0] : a0[0];
            const float hf = b4 ? a3[0] : a2[0];
            const float hg = b4 ? a5[0] : a4[0];
            const float ho = b4 ? a7[0] : a6[0];

            const f32x4 xg4 = *(const f32x4*)&xgw[tt * 132 + 4 * cc];  // broadcast pair-read
            const float gi = xg4[0] + hi;
            const float gf = xg4[1] + hf;
            const float gg = xg4[2] + hg;
            const float go = xg4[3] + ho;

            const float iv = sigm(gi);
            const float fv = sigm(gf);
            const float gv = fmaf(2.0f, sigm(2.0f * gg), -1.0f);   // tanh
            const float ov = sigm(go);
            c = fmaf(fv, c, iv * gv);
            const float th = fmaf(2.0f, sigm(2.0f * c), -1.0f);    // tanh
            h = ov * th;
            hw[cc] = f2bf(h);        // 2 lanes write same value: benign
        }
    }

    // ---- fused fc: out[b] = sum_cc h_cc * Wfc[cc] + bfc ----
    float p = (lane < 32) ? h * Wfc[cc] : 0.0f;
    #pragma unroll
    for (int msk = 16; msk >= 1; msk >>= 1) p += __shfl_xor(p, msk);
    if (lane == 0) out[b] = p + bfc[0];
}

extern "C" void kernel_launch(void* const* d_in, const int* in_sizes, int n_in,
                              void* d_out, int out_size, void* d_ws, size_t ws_size,
                              hipStream_t stream) {
    const float* x   = (const float*)d_in[0];
    const float* Wih = (const float*)d_in[1];
    const float* Whh = (const float*)d_in[2];
    const float* bih = (const float*)d_in[3];
    const float* bhh = (const float*)d_in[4];
    const float* Wfc = (const float*)d_in[5];
    const float* bfc = (const float*)d_in[6];
    float* out = (float*)d_out;
    lstm_fused<<<dim3(512), dim3(256), 0, stream>>>(x, Wih, Whh, bih, bhh, Wfc, bfc, out);
}

// Round 5
// 419.778 us; speedup vs baseline: 1.1679x; 1.0282x over previous
//
#include <hip/hip_runtime.h>

typedef __attribute__((ext_vector_type(8))) short short8;
typedef __attribute__((ext_vector_type(4))) float f32x4;

#define LOG2E 1.44269504088896340736f

__device__ __forceinline__ unsigned short f2bf(float f) {
    union { float f; unsigned u; } a; a.f = f;
    unsigned r = a.u + 0x7fffu + ((a.u >> 16) & 1u);   // RNE
    return (unsigned short)(r >> 16);
}
__device__ __forceinline__ unsigned pk2(float x, float y) {
    return (unsigned)f2bf(x) | ((unsigned)f2bf(y) << 16);
}
__device__ __forceinline__ float sigm(float x) {       // sigmoid via exp2+rcp
    return __builtin_amdgcn_rcpf(1.0f + __builtin_amdgcn_exp2f(-LOG2E * x));
}

// B=2048, T=512, I=64, H=32. TWO batch rows per wave: A-rows 0-7 = h(row0),
// 8-15 = h(row1) -> C-rows land row0 gates on lanes 0-31, row1 on lanes 32-63.
// Lane j owns column cc=j&31 of batch row rb=j>>5 (no redundant gate math).
__global__ __launch_bounds__(256, 1) void lstm_fused(
    const float* __restrict__ x,    // [2048,512,64]
    const float* __restrict__ Wih,  // [128,64]
    const float* __restrict__ Whh,  // [128,32]
    const float* __restrict__ bih,  // [128]
    const float* __restrict__ bhh,  // [128]
    const float* __restrict__ Wfc,  // [1,32]
    const float* __restrict__ bfc,  // [1]
    float* __restrict__ out)        // [2048,1]
{
    __shared__ unsigned short Wlds[128 * 80];            // W_ih bf16, stride 80   (20480 B)
    __shared__ float xg_sh[4 * 2 * 16 * 132];            // per-wave 2 rows xg     (67584 B)
    __shared__ alignas(64) unsigned short hbuf[4 * 64];  // per-wave h bf16 [rb*32+cc] (512 B)

    const int tid  = threadIdx.x;
    const int lane = tid & 63;
    const int wv   = tid >> 6;
    const int b0   = blockIdx.x * 8 + wv * 2;
    const int m    = lane & 15;   // tile col / A-row index
    const int quad = lane >> 4;   // k-quad
    const int cc   = lane & 31;   // owned h column
    const int rb   = lane >> 5;   // owned batch row (0/1)

    // ---- cooperative W_ih -> LDS (bf16, padded rows) ----
    {
        const float4* w4 = (const float4*)Wih;
        unsigned* wl = (unsigned*)Wlds;
        #pragma unroll
        for (int i = 0; i < 8; i++) {
            int fi = tid * 8 + i;            // float4 index, 2048 total
            int g  = fi >> 4;                // gate row
            int k  = (fi & 15) << 2;         // col (float units)
            float4 v = w4[fi];
            wl[g * 40 + (k >> 1) + 0] = pk2(v.x, v.y);
            wl[g * 40 + (k >> 1) + 1] = pk2(v.z, v.w);
        }
    }

    // ---- W_hh B-frags in registers (bf16): tile t, lane holds Whh[16t+m][quad*8..+7] ----
    short8 Bh[8];
    #pragma unroll
    for (int t = 0; t < 8; t++) {
        const float4* wr = (const float4*)(Whh + (size_t)(16 * t + m) * 32 + quad * 8);
        float4 va = wr[0], vb = wr[1];
        union { short8 v; unsigned u[4]; } B;
        B.u[0] = pk2(va.x, va.y); B.u[1] = pk2(va.z, va.w);
        B.u[2] = pk2(vb.x, vb.y); B.u[3] = pk2(vb.z, vb.w);
        Bh[t] = B.v;
    }

    // ---- per-lane scatter bias: biasv[n] = bih[16n+m]+bhh[16n+m] ----
    float biasv[8];
    #pragma unroll
    for (int n = 0; n < 8; n++) biasv[n] = bih[16 * n + m] + bhh[16 * n + m];

    const bool b4 = (lane & 16) != 0;

    __syncthreads();  // Wlds ready; per-wave regions need no further barriers

    const float* xrow0 = x + ((size_t)b0 * 512 + m) * 64;   // row b0, timestep row m
    const float* xrow1 = xrow0 + 512 * 64;                  // row b0+1
    float* xgw = xg_sh + wv * 4224;                         // [rb][16 t][132]
    unsigned short* hw = hbuf + wv * 64;                    // [rb*32+cc]

    hw[lane] = 0;               // h=0; index rb*32+cc == lane
    float c = 0.0f, h = 0.0f;
    const f32x4 z4 = {0.f, 0.f, 0.f, 0.f};

    // prefetch chunk 0, both rows
    float4 p0, p1, p2, p3, q0, q1, q2, q3;
    {
        const float4* r0 = (const float4*)xrow0;
        const float4* r1 = (const float4*)xrow1;
        p0 = r0[quad * 2];     p1 = r0[quad * 2 + 1];
        p2 = r0[8 + quad * 2]; p3 = r0[8 + quad * 2 + 1];
        q0 = r1[quad * 2];     q1 = r1[quad * 2 + 1];
        q2 = r1[8 + quad * 2]; q3 = r1[8 + quad * 2 + 1];
    }

    for (int ch = 0; ch < 32; ++ch) {
        // ---- pack both rows' A-frags (k 0..31, 32..63), bf16 ----
        union { short8 v; unsigned u[4]; } A0, A1, C0, C1;
        A0.u[0] = pk2(p0.x, p0.y); A0.u[1] = pk2(p0.z, p0.w);
        A0.u[2] = pk2(p1.x, p1.y); A0.u[3] = pk2(p1.z, p1.w);
        A1.u[0] = pk2(p2.x, p2.y); A1.u[1] = pk2(p2.z, p2.w);
        A1.u[2] = pk2(p3.x, p3.y); A1.u[3] = pk2(p3.z, p3.w);
        C0.u[0] = pk2(q0.x, q0.y); C0.u[1] = pk2(q0.z, q0.w);
        C0.u[2] = pk2(q1.x, q1.y); C0.u[3] = pk2(q1.z, q1.w);
        C1.u[0] = pk2(q2.x, q2.y); C1.u[1] = pk2(q2.z, q2.w);
        C1.u[2] = pk2(q3.x, q3.y); C1.u[3] = pk2(q3.z, q3.w);

        // ---- prefetch next chunk (hidden under the 16-step loop) ----
        {
            const int chn = (ch < 31) ? ch + 1 : 31;
            const float4* n0 = (const float4*)(xrow0 + (size_t)chn * 1024);
            const float4* n1 = (const float4*)(xrow1 + (size_t)chn * 1024);
            p0 = n0[quad * 2];     p1 = n0[quad * 2 + 1];
            p2 = n0[8 + quad * 2]; p3 = n0[8 + quad * 2 + 1];
            q0 = n1[quad * 2];     q1 = n1[quad * 2 + 1];
            q2 = n1[8 + quad * 2]; q3 = n1[8 + quad * 2 + 1];
        }

        // ---- xg for both rows: 32 MFMAs, B-frags shared; scatter [tt][4*cc+gidx] ----
        #pragma unroll
        for (int n = 0; n < 8; n++) {
            const short8 B0 = *(const short8*)&Wlds[(16 * n + m) * 80 + quad * 8];
            const short8 B1 = *(const short8*)&Wlds[(16 * n + m) * 80 + 32 + quad * 8];
            f32x4 ar0 = {0.f, 0.f, 0.f, 0.f};
            ar0 = __builtin_amdgcn_mfma_f32_16x16x32_bf16(A0.v, B0, ar0, 0, 0, 0);
            ar0 = __builtin_amdgcn_mfma_f32_16x16x32_bf16(A1.v, B1, ar0, 0, 0, 0);
            f32x4 ar1 = {0.f, 0.f, 0.f, 0.f};
            ar1 = __builtin_amdgcn_mfma_f32_16x16x32_bf16(C0.v, B0, ar1, 0, 0, 0);
            ar1 = __builtin_amdgcn_mfma_f32_16x16x32_bf16(C1.v, B1, ar1, 0, 0, 0);
            const int pos = ((n & 1) << 6) + 4 * m + (n >> 1);
            #pragma unroll
            for (int r = 0; r < 4; r++) {
                xgw[(quad * 4 + r) * 132 + pos]        = ar0[r] + biasv[n];
                xgw[2112 + (quad * 4 + r) * 132 + pos] = ar1[r] + biasv[n];
            }
        }

        // ---- 16 recurrent timesteps ----
        #pragma unroll
        for (int tt = 0; tt < 16; ++tt) {
            // A row m = h of batch row m>>3; lane reads its k-chunk quad*8..+7
            const short8 abf = *(const short8*)&hw[((m >> 3) << 5) + quad * 8];
            const f32x4 a0 = __builtin_amdgcn_mfma_f32_16x16x32_bf16(abf, Bh[0], z4, 0, 0, 0);
            const f32x4 a1 = __builtin_amdgcn_mfma_f32_16x16x32_bf16(abf, Bh[1], z4, 0, 0, 0);
            const f32x4 a2 = __builtin_amdgcn_mfma_f32_16x16x32_bf16(abf, Bh[2], z4, 0, 0, 0);
            const f32x4 a3 = __builtin_amdgcn_mfma_f32_16x16x32_bf16(abf, Bh[3], z4, 0, 0, 0);
            const f32x4 a4 = __builtin_amdgcn_mfma_f32_16x16x32_bf16(abf, Bh[4], z4, 0, 0, 0);
            const f32x4 a5 = __builtin_amdgcn_mfma_f32_16x16x32_bf16(abf, Bh[5], z4, 0, 0, 0);
            const f32x4 a6 = __builtin_amdgcn_mfma_f32_16x16x32_bf16(abf, Bh[6], z4, 0, 0, 0);
            const f32x4 a7 = __builtin_amdgcn_mfma_f32_16x16x32_bf16(abf, Bh[7], z4, 0, 0, 0);
            // lane's gates (own row via quad-half): i=cc (tile b4), f=cc+32, g=cc+64, o=cc+96
            const float hi = b4 ? a1[0] : a0[0];
            const float hf = b4 ? a3[0] : a2[0];
            const float hg = b4 ? a5[0] : a4[0];
            const float ho = b4 ? a7[0] : a6[0];

            const f32x4 xg4 = *(const f32x4*)&xgw[rb * 2112 + tt * 132 + 4 * cc];
            const float gi = xg4[0] + hi;
            const float gf = xg4[1] + hf;
            const float gg = xg4[2] + hg;
            const float go = xg4[3] + ho;

            const float iv = sigm(gi);
            const float fv = sigm(gf);
            const float gv = fmaf(2.0f, sigm(2.0f * gg), -1.0f);   // tanh
            const float ov = sigm(go);
            c = fmaf(fv, c, iv * gv);
            const float th = fmaf(2.0f, sigm(2.0f * c), -1.0f);    // tanh
            h = ov * th;
            hw[lane] = f2bf(h);      // [rb*32+cc]
        }
    }

    // ---- fused fc: out[b0+rb] = sum_cc h_cc * Wfc[cc] + bfc (per half-wave) ----
    float p = h * Wfc[cc];
    #pragma unroll
    for (int msk = 16; msk >= 1; msk >>= 1) p += __shfl_xor(p, msk);
    if ((lane & 31) == 0) out[b0 + rb] = p + bfc[0];
}

extern "C" void kernel_launch(void* const* d_in, const int* in_sizes, int n_in,
                              void* d_out, int out_size, void* d_ws, size_t ws_size,
                              hipStream_t stream) {
    const float* x   = (const float*)d_in[0];
    const float* Wih = (const float*)d_in[1];
    const float* Whh = (const float*)d_in[2];
    const float* bih = (const float*)d_in[3];
    const float* bhh = (const float*)d_in[4];
    const float* Wfc = (const float*)d_in[5];
    const float* bfc = (const float*)d_in[6];
    float* out = (float*)d_out;
    lstm_fused<<<dim3(256), dim3(256), 0, stream>>>(x, Wih, Whh, bih, bhh, Wfc, bfc, out);
}